// Round 1
// baseline (879.333 us; speedup 1.0000x reference)
//
#include <hip/hip_runtime.h>

#define NM 2048
#define EM 32768
#define NP 8192
#define EP 262144

// ---------------- edge aggregation: msg = relu(x[src]+ea), atomic mean parts ----------------
__global__ __launch_bounds__(256) void edge_aggr_kernel(
    const float* __restrict__ x, const int* __restrict__ ei, const float* __restrict__ ea,
    float* __restrict__ ssum, float* __restrict__ cnt, int E)
{
    int idx = blockIdx.x * 256 + threadIdx.x;
    int total = E * 64;
    if (idx >= total) return;
    int e = idx >> 6;
    int c = idx & 63;
    int s = ei[e];
    int d = ei[E + e];
    float m = x[s * 64 + c] + ea[idx];
    m = fmaxf(m, 0.0f);
    atomicAdd(&ssum[d * 64 + c], m);
    if (c == 0) atomicAdd(&cnt[d], 1.0f);
}

// ---------------- GINE node update: h = relu( relu((x+aggr)@w1+b1)@w2 + b2 ) ----------------
__global__ __launch_bounds__(256) void gine_mlp_kernel(
    const float* __restrict__ x, const float* __restrict__ ssum, const float* __restrict__ cnt,
    const float* __restrict__ w1, const float* __restrict__ b1,
    const float* __restrict__ w2, const float* __restrict__ b2,
    float* __restrict__ out)
{
    __shared__ float sW1[4096], sW2[4096], sb1[64], sb2[64];
    __shared__ float sh0[16][64], sh1[16][64];
    int t = threadIdx.x;
    for (int i = t; i < 4096; i += 256) { sW1[i] = w1[i]; sW2[i] = w2[i]; }
    if (t < 64) { sb1[t] = b1[t]; sb2[t] = b2[t]; }
    int row0 = blockIdx.x * 16;
    for (int i = t; i < 16 * 64; i += 256) {
        int r = i >> 6, c = i & 63;
        int row = row0 + r;
        float cn = fmaxf(cnt[row], 1.0f);
        sh0[r][c] = x[row * 64 + c] + ssum[row * 64 + c] / cn;
    }
    __syncthreads();
    int j = t & 63, rs = t >> 6;
    for (int r = rs; r < 16; r += 4) {
        float a = sb1[j];
        #pragma unroll
        for (int c = 0; c < 64; c++) a += sh0[r][c] * sW1[c * 64 + j];
        sh1[r][j] = fmaxf(a, 0.0f);
    }
    __syncthreads();
    for (int r = rs; r < 16; r += 4) {
        float a = sb2[j];
        #pragma unroll
        for (int c = 0; c < 64; c++) a += sh1[r][c] * sW2[c * 64 + j];
        out[(size_t)(row0 + r) * 64 + j] = fmaxf(a, 0.0f);   // outer relu fused
    }
}

// ---------------- fused 3x linear: Q = h@wq+bq, K = h@wk+bk, V = h@wv+bv ----------------
__global__ __launch_bounds__(256) void qkv_kernel(
    const float* __restrict__ x,
    const float* __restrict__ wq, const float* __restrict__ bq,
    const float* __restrict__ wk, const float* __restrict__ bk,
    const float* __restrict__ wv, const float* __restrict__ bv,
    float* __restrict__ Q, float* __restrict__ K, float* __restrict__ V)
{
    __shared__ float sWq[4096], sWk[4096], sWv[4096];
    __shared__ float sbq[64], sbk[64], sbv[64];
    __shared__ float sh0[16][64];
    int t = threadIdx.x;
    for (int i = t; i < 4096; i += 256) { sWq[i] = wq[i]; sWk[i] = wk[i]; sWv[i] = wv[i]; }
    if (t < 64) { sbq[t] = bq[t]; sbk[t] = bk[t]; sbv[t] = bv[t]; }
    int row0 = blockIdx.x * 16;
    for (int i = t; i < 16 * 64; i += 256) {
        int r = i >> 6, c = i & 63;
        sh0[r][c] = x[(size_t)(row0 + r) * 64 + c];
    }
    __syncthreads();
    int j = t & 63, rs = t >> 6;
    for (int r = rs; r < 16; r += 4) {
        float aq = sbq[j], ak = sbk[j], av = sbv[j];
        #pragma unroll
        for (int c = 0; c < 64; c++) {
            float h = sh0[r][c];
            aq += h * sWq[c * 64 + j];
            ak += h * sWk[c * 64 + j];
            av += h * sWv[c * 64 + j];
        }
        size_t o = (size_t)(row0 + r) * 64 + j;
        Q[o] = aq; K[o] = ak; V[o] = av;
    }
}

// ---------------- cross-attention, fp32 online softmax ----------------
// grid: (Nq/16, H); block 256 = 16 queries x 16 key-slices
__global__ __launch_bounds__(256) void attn_kernel(
    const float* __restrict__ Q, const float* __restrict__ K, const float* __restrict__ V,
    float* __restrict__ out, int Nk)
{
    __shared__ float red[16][16][18];
    int t = threadIdx.x;
    int ql = t & 15;
    int sl = t >> 4;
    int h = blockIdx.y;
    int q0 = blockIdx.x * 16;
    const float* qp = Q + (size_t)(q0 + ql) * 64 + h * 16;
    float4 qa = *(const float4*)(qp);
    float4 qb = *(const float4*)(qp + 4);
    float4 qc = *(const float4*)(qp + 8);
    float4 qd = *(const float4*)(qp + 12);
    float m = -3.0e38f, l = 0.0f;
    float acc[16];
    #pragma unroll
    for (int i = 0; i < 16; i++) acc[i] = 0.0f;
    for (int k = sl; k < Nk; k += 16) {
        const float* kp = K + (size_t)k * 64 + h * 16;
        float4 k0 = *(const float4*)(kp);
        float4 k1 = *(const float4*)(kp + 4);
        float4 k2 = *(const float4*)(kp + 8);
        float4 k3 = *(const float4*)(kp + 12);
        const float* vp = V + (size_t)k * 64 + h * 16;
        float4 v0 = *(const float4*)(vp);
        float4 v1 = *(const float4*)(vp + 4);
        float4 v2 = *(const float4*)(vp + 8);
        float4 v3 = *(const float4*)(vp + 12);
        float s = (qa.x * k0.x + qa.y * k0.y + qa.z * k0.z + qa.w * k0.w)
                + (qb.x * k1.x + qb.y * k1.y + qb.z * k1.z + qb.w * k1.w)
                + (qc.x * k2.x + qc.y * k2.y + qc.z * k2.z + qc.w * k2.w)
                + (qd.x * k3.x + qd.y * k3.y + qd.z * k3.z + qd.w * k3.w);
        s *= 0.25f;
        float mn = fmaxf(m, s);
        float alpha = __expf(m - mn);
        float p = __expf(s - mn);
        l = l * alpha + p;
        acc[0]  = acc[0]  * alpha + p * v0.x;
        acc[1]  = acc[1]  * alpha + p * v0.y;
        acc[2]  = acc[2]  * alpha + p * v0.z;
        acc[3]  = acc[3]  * alpha + p * v0.w;
        acc[4]  = acc[4]  * alpha + p * v1.x;
        acc[5]  = acc[5]  * alpha + p * v1.y;
        acc[6]  = acc[6]  * alpha + p * v1.z;
        acc[7]  = acc[7]  * alpha + p * v1.w;
        acc[8]  = acc[8]  * alpha + p * v2.x;
        acc[9]  = acc[9]  * alpha + p * v2.y;
        acc[10] = acc[10] * alpha + p * v2.z;
        acc[11] = acc[11] * alpha + p * v2.w;
        acc[12] = acc[12] * alpha + p * v3.x;
        acc[13] = acc[13] * alpha + p * v3.y;
        acc[14] = acc[14] * alpha + p * v3.z;
        acc[15] = acc[15] * alpha + p * v3.w;
        m = mn;
    }
    float* slot = &red[ql][sl][0];
    slot[0] = m; slot[1] = l;
    #pragma unroll
    for (int i = 0; i < 16; i++) slot[2 + i] = acc[i];
    __syncthreads();
    for (int step = 8; step >= 1; step >>= 1) {
        if (sl < step) {
            float* a = &red[ql][sl][0];
            float* b = &red[ql][sl + step][0];
            float ma = a[0], mb = b[0];
            float mn = fmaxf(ma, mb);
            float aa = __expf(ma - mn), ab = __expf(mb - mn);
            a[0] = mn;
            a[1] = a[1] * aa + b[1] * ab;
            #pragma unroll
            for (int i = 0; i < 16; i++) a[2 + i] = a[2 + i] * aa + b[2 + i] * ab;
        }
        __syncthreads();
    }
    int q = t >> 4, dd = t & 15;
    out[(size_t)(q0 + q) * 64 + h * 16 + dd] = red[q][0][2 + dd] / red[q][0][1];
}

// ---------------- layernorm(h + attn) ----------------
__global__ __launch_bounds__(256) void ln_kernel(
    const float* __restrict__ h, const float* __restrict__ attn,
    const float* __restrict__ g, const float* __restrict__ b,
    float* __restrict__ out)
{
    int row = blockIdx.x * 4 + (threadIdx.x >> 6);
    int c = threadIdx.x & 63;
    float v = h[(size_t)row * 64 + c] + attn[(size_t)row * 64 + c];
    float s = v;
    #pragma unroll
    for (int o = 32; o >= 1; o >>= 1) s += __shfl_xor(s, o, 64);
    float mu = s * (1.0f / 64.0f);
    float d = v - mu;
    float sq = d * d;
    #pragma unroll
    for (int o = 32; o >= 1; o >>= 1) sq += __shfl_xor(sq, o, 64);
    float var = sq * (1.0f / 64.0f);
    out[(size_t)row * 64 + c] = d * rsqrtf(var + 1e-5f) * g[c] + b[c];
}

extern "C" void kernel_launch(void* const* d_in, const int* in_sizes, int n_in,
                              void* d_out, int out_size, void* d_ws, size_t ws_size,
                              hipStream_t stream)
{
    const float* x_mol   = (const float*)d_in[0];
    const int*   ei_mol  = (const int*)  d_in[1];
    const float* ea_mol  = (const float*)d_in[2];
    const float* x_prot  = (const float*)d_in[3];
    const int*   ei_prot = (const int*)  d_in[4];
    const float* ea_prot = (const float*)d_in[5];
    const float* mol_w1  = (const float*)d_in[6];
    const float* mol_b1  = (const float*)d_in[7];
    const float* mol_w2  = (const float*)d_in[8];
    const float* mol_b2  = (const float*)d_in[9];
    const float* prot_w1 = (const float*)d_in[10];
    const float* prot_b1 = (const float*)d_in[11];
    const float* prot_w2 = (const float*)d_in[12];
    const float* prot_b2 = (const float*)d_in[13];
    const float* mp_wq = (const float*)d_in[14]; const float* mp_bq = (const float*)d_in[15];
    const float* mp_wk = (const float*)d_in[16]; const float* mp_bk = (const float*)d_in[17];
    const float* mp_wv = (const float*)d_in[18]; const float* mp_bv = (const float*)d_in[19];
    const float* pm_wq = (const float*)d_in[20]; const float* pm_bq = (const float*)d_in[21];
    const float* pm_wk = (const float*)d_in[22]; const float* pm_bk = (const float*)d_in[23];
    const float* pm_wv = (const float*)d_in[24]; const float* pm_bv = (const float*)d_in[25];
    const float* ln_mol_g  = (const float*)d_in[26];
    const float* ln_mol_b  = (const float*)d_in[27];
    const float* ln_prot_g = (const float*)d_in[28];
    const float* ln_prot_b = (const float*)d_in[29];

    float* ws = (float*)d_ws;
    float* ssum_mol  = ws;                     // 131072
    float* ssum_prot = ssum_mol + 131072;      // 524288
    float* cnt_mol   = ssum_prot + 524288;     // 2048
    float* cnt_prot  = cnt_mol + 2048;         // 8192
    float* h_mol     = cnt_prot + 8192;        // 131072
    float* h_prot    = h_mol + 131072;         // 524288
    float* Qm        = h_prot + 524288;        // 131072
    float* Km        = Qm + 131072;            // 131072
    float* Vm        = Km + 131072;            // 131072
    float* Qp        = Vm + 131072;            // 524288
    float* Kp        = Qp + 524288;            // 524288
    float* Vp        = Kp + 524288;            // 524288
    float* attn_mol  = Vp + 524288;            // 131072
    float* attn_prot = attn_mol + 131072;      // 524288

    // zero the atomic-accumulation region (ssum_mol..cnt_prot is contiguous)
    hipMemsetAsync(ws, 0, (size_t)(131072 + 524288 + 2048 + 8192) * sizeof(float), stream);

    edge_aggr_kernel<<<EM * 64 / 256, 256, 0, stream>>>(x_mol, ei_mol, ea_mol, ssum_mol, cnt_mol, EM);
    edge_aggr_kernel<<<EP * 64 / 256, 256, 0, stream>>>(x_prot, ei_prot, ea_prot, ssum_prot, cnt_prot, EP);

    gine_mlp_kernel<<<NM / 16, 256, 0, stream>>>(x_mol, ssum_mol, cnt_mol, mol_w1, mol_b1, mol_w2, mol_b2, h_mol);
    gine_mlp_kernel<<<NP / 16, 256, 0, stream>>>(x_prot, ssum_prot, cnt_prot, prot_w1, prot_b1, prot_w2, prot_b2, h_prot);

    // mol-source projections: Q for mol->prot, K/V for prot->mol
    qkv_kernel<<<NM / 16, 256, 0, stream>>>(h_mol, mp_wq, mp_bq, pm_wk, pm_bk, pm_wv, pm_bv, Qm, Km, Vm);
    // prot-source projections: Q for prot->mol, K/V for mol->prot
    qkv_kernel<<<NP / 16, 256, 0, stream>>>(h_prot, pm_wq, pm_bq, mp_wk, mp_bk, mp_wv, mp_bv, Qp, Kp, Vp);

    dim3 gm(NM / 16, 4);
    attn_kernel<<<gm, 256, 0, stream>>>(Qm, Kp, Vp, attn_mol, NP);
    dim3 gp(NP / 16, 4);
    attn_kernel<<<gp, 256, 0, stream>>>(Qp, Km, Vm, attn_prot, NM);

    float* out = (float*)d_out;
    ln_kernel<<<NM / 4, 256, 0, stream>>>(h_mol, attn_mol, ln_mol_g, ln_mol_b, out);
    ln_kernel<<<NP / 4, 256, 0, stream>>>(h_prot, attn_prot, ln_prot_g, ln_prot_b, out + 131072);
}

// Round 2
// 348.843 us; speedup vs baseline: 2.5207x; 2.5207x over previous
//
#include <hip/hip_runtime.h>

#define NM 2048
#define EM 32768
#define NP 8192
#define EP 262144

typedef __attribute__((ext_vector_type(8))) short short8;
typedef __attribute__((ext_vector_type(4))) short short4v;
typedef __attribute__((ext_vector_type(4))) float f32x4;

__device__ __forceinline__ unsigned short f2bf(float f) {
    unsigned int u = __float_as_uint(f);
    u = (u + 0x7fff + ((u >> 16) & 1)) >> 16;   // RNE
    return (unsigned short)u;
}

// ---------------- edge aggregation: msg = relu(x[src]+ea), atomic mean parts ----------------
__global__ __launch_bounds__(256) void edge_aggr_kernel(
    const float* __restrict__ x, const int* __restrict__ ei, const float* __restrict__ ea,
    float* __restrict__ ssum, float* __restrict__ cnt, int E)
{
    int idx = blockIdx.x * 256 + threadIdx.x;
    int total = E * 64;
    if (idx >= total) return;
    int e = idx >> 6;
    int c = idx & 63;
    int s = ei[e];
    int d = ei[E + e];
    float m = x[s * 64 + c] + ea[idx];
    m = fmaxf(m, 0.0f);
    atomicAdd(&ssum[d * 64 + c], m);
    if (c == 0) atomicAdd(&cnt[d], 1.0f);
}

// ---------------- GINE node update: h = relu( relu((x+aggr)@w1+b1)@w2 + b2 ) ----------------
__global__ __launch_bounds__(256) void gine_mlp_kernel(
    const float* __restrict__ x, const float* __restrict__ ssum, const float* __restrict__ cnt,
    const float* __restrict__ w1, const float* __restrict__ b1,
    const float* __restrict__ w2, const float* __restrict__ b2,
    float* __restrict__ out)
{
    __shared__ float sW1[4096], sW2[4096], sb1[64], sb2[64];
    __shared__ float sh0[16][64], sh1[16][64];
    int t = threadIdx.x;
    for (int i = t; i < 4096; i += 256) { sW1[i] = w1[i]; sW2[i] = w2[i]; }
    if (t < 64) { sb1[t] = b1[t]; sb2[t] = b2[t]; }
    int row0 = blockIdx.x * 16;
    for (int i = t; i < 16 * 64; i += 256) {
        int r = i >> 6, c = i & 63;
        int row = row0 + r;
        float cn = fmaxf(cnt[row], 1.0f);
        sh0[r][c] = x[row * 64 + c] + ssum[row * 64 + c] / cn;
    }
    __syncthreads();
    int j = t & 63, rs = t >> 6;
    for (int r = rs; r < 16; r += 4) {
        float a = sb1[j];
        #pragma unroll
        for (int c = 0; c < 64; c++) a += sh0[r][c] * sW1[c * 64 + j];
        sh1[r][j] = fmaxf(a, 0.0f);
    }
    __syncthreads();
    for (int r = rs; r < 16; r += 4) {
        float a = sb2[j];
        #pragma unroll
        for (int c = 0; c < 64; c++) a += sh1[r][c] * sW2[c * 64 + j];
        out[(size_t)(row0 + r) * 64 + j] = fmaxf(a, 0.0f);   // outer relu fused
    }
}

// -------- fused 3x linear -> bf16: Q = 0.25*(h@wq+bq), K = h@wk+bk, Vt = (h@wv+bv)^T --------
__global__ __launch_bounds__(256) void qkv_bf16_kernel(
    const float* __restrict__ x,
    const float* __restrict__ wq, const float* __restrict__ bq,
    const float* __restrict__ wk, const float* __restrict__ bk,
    const float* __restrict__ wv, const float* __restrict__ bv,
    unsigned short* __restrict__ Q, unsigned short* __restrict__ K,
    unsigned short* __restrict__ Vt, int N)
{
    __shared__ float sWq[4096], sWk[4096], sWv[4096];
    __shared__ float sbq[64], sbk[64], sbv[64];
    __shared__ float sh0[16][64];
    int t = threadIdx.x;
    for (int i = t; i < 4096; i += 256) { sWq[i] = wq[i]; sWk[i] = wk[i]; sWv[i] = wv[i]; }
    if (t < 64) { sbq[t] = bq[t]; sbk[t] = bk[t]; sbv[t] = bv[t]; }
    int row0 = blockIdx.x * 16;
    for (int i = t; i < 16 * 64; i += 256) {
        int r = i >> 6, c = i & 63;
        sh0[r][c] = x[(size_t)(row0 + r) * 64 + c];
    }
    __syncthreads();
    int j = t & 63, rs = t >> 6;
    for (int r = rs; r < 16; r += 4) {
        float aq = sbq[j], ak = sbk[j], av = sbv[j];
        #pragma unroll
        for (int c = 0; c < 64; c++) {
            float h = sh0[r][c];
            aq += h * sWq[c * 64 + j];
            ak += h * sWk[c * 64 + j];
            av += h * sWv[c * 64 + j];
        }
        size_t o = (size_t)(row0 + r) * 64 + j;
        Q[o] = f2bf(aq * 0.25f);              // fold 1/sqrt(HD)
        K[o] = f2bf(ak);
        Vt[(size_t)j * N + row0 + r] = f2bf(av);
    }
}

// ---------------- MFMA flash-attention partial over a 1024-key chunk ----------------
// task = ((qt*4 + h)*NC + chunk); wave per task; S^T = K.Q^T trick keeps softmax per-lane.
__global__ __launch_bounds__(256) void attn_partial_kernel(
    const unsigned short* __restrict__ Q, const unsigned short* __restrict__ K,
    const unsigned short* __restrict__ Vt, float* __restrict__ partial,
    int Nk, int ncbits)
{
    __shared__ unsigned short plds[4][16][40];   // per-wave P tile, keys 0..31 + pad
    int t = threadIdx.x;
    int wave = t >> 6;
    int lane = t & 63;
    int qrow = lane & 15;          // query (and d, and key-row) index within tile
    int quad = lane >> 4;
    int NC = 1 << ncbits;
    int task = blockIdx.x * 4 + wave;
    int chunk = task & (NC - 1);
    int tmp = task >> ncbits;
    int h = tmp & 3;
    int qt = tmp >> 2;

    // Q fragment (B operand): B[k=quad*8+j][n=q] = Q[q][dim quad*8+j]; quads 2,3 are pad
    short8 qf = {};
    if (quad < 2)
        qf = *(const short8*)(Q + ((size_t)(qt * 16 + qrow)) * 64 + h * 16 + quad * 8);

    float m = -3.0e38f, l = 0.0f;
    f32x4 acc = {0.f, 0.f, 0.f, 0.f};
    const f32x4 zero4 = {0.f, 0.f, 0.f, 0.f};
    int kbase = chunk * 1024;

    for (int it = 0; it < 32; ++it) {
        int key0 = kbase + it * 32;
        // K fragments (A operand of S^T): A[m=key][k=dim], quads 2,3 pad
        short8 kf0 = {}, kf1 = {};
        if (quad < 2) {
            kf0 = *(const short8*)(K + ((size_t)(key0 + qrow)) * 64 + h * 16 + quad * 8);
            kf1 = *(const short8*)(K + ((size_t)(key0 + 16 + qrow)) * 64 + h * 16 + quad * 8);
        }
        // Vt fragment (A operand of O^T): A[m=d][k=key] = V[key][d]
        short8 vf = *(const short8*)(Vt + ((size_t)(h * 16 + qrow)) * Nk + key0 + quad * 8);

        // S^T tiles: s0[r] = score(key0+4*quad+r, q=qrow), s1 = +16
        f32x4 s0 = __builtin_amdgcn_mfma_f32_16x16x32_bf16(kf0, qf, zero4, 0, 0, 0);
        f32x4 s1 = __builtin_amdgcn_mfma_f32_16x16x32_bf16(kf1, qf, zero4, 0, 0, 0);

        float tmax = fmaxf(fmaxf(fmaxf(s0.x, s0.y), fmaxf(s0.z, s0.w)),
                           fmaxf(fmaxf(s1.x, s1.y), fmaxf(s1.z, s1.w)));
        tmax = fmaxf(tmax, __shfl_xor(tmax, 16, 64));
        tmax = fmaxf(tmax, __shfl_xor(tmax, 32, 64));
        float mnew = fmaxf(m, tmax);
        float alpha = __expf(m - mnew);
        float p00 = __expf(s0.x - mnew), p01 = __expf(s0.y - mnew);
        float p02 = __expf(s0.z - mnew), p03 = __expf(s0.w - mnew);
        float p10 = __expf(s1.x - mnew), p11 = __expf(s1.y - mnew);
        float p12 = __expf(s1.z - mnew), p13 = __expf(s1.w - mnew);
        l = l * alpha + (((p00 + p01) + (p02 + p03)) + ((p10 + p11) + (p12 + p13)));
        acc.x *= alpha; acc.y *= alpha; acc.z *= alpha; acc.w *= alpha;

        // P (bf16) -> LDS in [q][key] order, read back as B operand of O^T
        short4v pk0, pk1;
        pk0.x = (short)f2bf(p00); pk0.y = (short)f2bf(p01);
        pk0.z = (short)f2bf(p02); pk0.w = (short)f2bf(p03);
        pk1.x = (short)f2bf(p10); pk1.y = (short)f2bf(p11);
        pk1.z = (short)f2bf(p12); pk1.w = (short)f2bf(p13);
        *(short4v*)&plds[wave][qrow][quad * 4] = pk0;        // keys 4*quad..+3
        *(short4v*)&plds[wave][qrow][16 + quad * 4] = pk1;   // keys 16+4*quad..+3
        short8 pf = *(short8*)&plds[wave][qrow][quad * 8];   // B[k=quad*8+j][n=q]

        acc = __builtin_amdgcn_mfma_f32_16x16x32_bf16(vf, pf, acc, 0, 0, 0);
        m = mnew;
    }

    // l is a per-quad partial (each lane covered 8 of every 32 keys)
    float ltot = l + __shfl_xor(l, 16, 64);
    ltot += __shfl_xor(ltot, 32, 64);

    float* pb = partial + (size_t)task * 288;
    *(f32x4*)&pb[qrow * 16 + quad * 4] = acc;    // acc[r] = O[q][d=4*quad+r] (unnormalized)
    if (quad == 0) { pb[256 + qrow] = m; pb[272 + qrow] = ltot; }
}

// ---------------- merge chunk partials + residual + layernorm ----------------
__global__ __launch_bounds__(256) void merge_ln_kernel(
    const float* __restrict__ partial, const float* __restrict__ hbuf,
    const float* __restrict__ g, const float* __restrict__ bia,
    float* __restrict__ out, int NC)
{
    int row = blockIdx.x * 4 + (threadIdx.x >> 6);
    int c = threadIdx.x & 63;
    int hi = c >> 4, d = c & 15;
    int qt = row >> 4, ql = row & 15;
    const float* base = partial + (size_t)(qt * 4 + hi) * NC * 288;
    float M = -3.0e38f;
    for (int cc = 0; cc < NC; ++cc) M = fmaxf(M, base[cc * 288 + 256 + ql]);
    float L = 0.0f, A = 0.0f;
    for (int cc = 0; cc < NC; ++cc) {
        float w = __expf(base[cc * 288 + 256 + ql] - M);
        L += base[cc * 288 + 272 + ql] * w;
        A += base[cc * 288 + ql * 16 + d] * w;
    }
    float v = hbuf[(size_t)row * 64 + c] + A / L;
    float s = v;
    #pragma unroll
    for (int o = 32; o >= 1; o >>= 1) s += __shfl_xor(s, o, 64);
    float mu = s * (1.0f / 64.0f);
    float dv = v - mu;
    float sq = dv * dv;
    #pragma unroll
    for (int o = 32; o >= 1; o >>= 1) sq += __shfl_xor(sq, o, 64);
    float var = sq * (1.0f / 64.0f);
    out[(size_t)row * 64 + c] = dv * rsqrtf(var + 1e-5f) * g[c] + bia[c];
}

extern "C" void kernel_launch(void* const* d_in, const int* in_sizes, int n_in,
                              void* d_out, int out_size, void* d_ws, size_t ws_size,
                              hipStream_t stream)
{
    const float* x_mol   = (const float*)d_in[0];
    const int*   ei_mol  = (const int*)  d_in[1];
    const float* ea_mol  = (const float*)d_in[2];
    const float* x_prot  = (const float*)d_in[3];
    const int*   ei_prot = (const int*)  d_in[4];
    const float* ea_prot = (const float*)d_in[5];
    const float* mol_w1  = (const float*)d_in[6];
    const float* mol_b1  = (const float*)d_in[7];
    const float* mol_w2  = (const float*)d_in[8];
    const float* mol_b2  = (const float*)d_in[9];
    const float* prot_w1 = (const float*)d_in[10];
    const float* prot_b1 = (const float*)d_in[11];
    const float* prot_w2 = (const float*)d_in[12];
    const float* prot_b2 = (const float*)d_in[13];
    const float* mp_wq = (const float*)d_in[14]; const float* mp_bq = (const float*)d_in[15];
    const float* mp_wk = (const float*)d_in[16]; const float* mp_bk = (const float*)d_in[17];
    const float* mp_wv = (const float*)d_in[18]; const float* mp_bv = (const float*)d_in[19];
    const float* pm_wq = (const float*)d_in[20]; const float* pm_bq = (const float*)d_in[21];
    const float* pm_wk = (const float*)d_in[22]; const float* pm_bk = (const float*)d_in[23];
    const float* pm_wv = (const float*)d_in[24]; const float* pm_bv = (const float*)d_in[25];
    const float* ln_mol_g  = (const float*)d_in[26];
    const float* ln_mol_b  = (const float*)d_in[27];
    const float* ln_prot_g = (const float*)d_in[28];
    const float* ln_prot_b = (const float*)d_in[29];

    float* ws = (float*)d_ws;
    float* ssum_mol  = ws;                       // 131072
    float* ssum_prot = ssum_mol + 131072;        // 524288
    float* cnt_mol   = ssum_prot + 524288;       // 2048
    float* cnt_prot  = cnt_mol + 2048;           // 8192
    float* h_mol     = cnt_prot + 8192;          // 131072
    float* h_prot    = h_mol + 131072;           // 524288
    float* partial   = h_prot + 524288;          // 4096*288 = 1179648 (reused per direction)
    unsigned short* bf = (unsigned short*)(partial + 1179648);
    unsigned short* Qm  = bf;                    // 131072 bf16
    unsigned short* Km  = Qm + 131072;
    unsigned short* Vtm = Km + 131072;           // [64][NM]
    unsigned short* Qp  = Vtm + 131072;          // 524288 bf16
    unsigned short* Kp  = Qp + 524288;
    unsigned short* Vtp = Kp + 524288;           // [64][NP]

    // zero the atomic-accumulation region (ssum..cnt contiguous)
    hipMemsetAsync(ws, 0, (size_t)(131072 + 524288 + 2048 + 8192) * sizeof(float), stream);

    edge_aggr_kernel<<<EM * 64 / 256, 256, 0, stream>>>(x_mol, ei_mol, ea_mol, ssum_mol, cnt_mol, EM);
    edge_aggr_kernel<<<EP * 64 / 256, 256, 0, stream>>>(x_prot, ei_prot, ea_prot, ssum_prot, cnt_prot, EP);

    gine_mlp_kernel<<<NM / 16, 256, 0, stream>>>(x_mol, ssum_mol, cnt_mol, mol_w1, mol_b1, mol_w2, mol_b2, h_mol);
    gine_mlp_kernel<<<NP / 16, 256, 0, stream>>>(x_prot, ssum_prot, cnt_prot, prot_w1, prot_b1, prot_w2, prot_b2, h_prot);

    // mol-source: Q for mol->prot, K/V for prot->mol
    qkv_bf16_kernel<<<NM / 16, 256, 0, stream>>>(h_mol, mp_wq, mp_bq, pm_wk, pm_bk, pm_wv, pm_bv, Qm, Km, Vtm, NM);
    // prot-source: Q for prot->mol, K/V for mol->prot
    qkv_bf16_kernel<<<NP / 16, 256, 0, stream>>>(h_prot, pm_wq, pm_bq, mp_wk, mp_bk, mp_wv, mp_bv, Qp, Kp, Vtp, NP);

    float* out = (float*)d_out;

    // mol->prot: Nq=2048 (128 qt), Nk=8192, NC=8 chunks of 1024 -> 4096 tasks
    attn_partial_kernel<<<1024, 256, 0, stream>>>(Qm, Kp, Vtp, partial, NP, 3);
    merge_ln_kernel<<<NM / 4, 256, 0, stream>>>(partial, h_mol, ln_mol_g, ln_mol_b, out, 8);

    // prot->mol: Nq=8192 (512 qt), Nk=2048, NC=2 chunks of 1024 -> 4096 tasks
    attn_partial_kernel<<<1024, 256, 0, stream>>>(Qp, Km, Vtm, partial, NM, 1);
    merge_ln_kernel<<<NP / 4, 256, 0, stream>>>(partial, h_prot, ln_prot_g, ln_prot_b, out + 131072, 2);
}

// Round 3
// 333.181 us; speedup vs baseline: 2.6392x; 1.0470x over previous
//
#include <hip/hip_runtime.h>
#include <hip/hip_bf16.h>

#define NM 2048
#define EM 32768
#define NP 8192
#define EP 262144

typedef __attribute__((ext_vector_type(8))) short short8;
typedef __attribute__((ext_vector_type(4))) float f32x4;

#define LOG2E 1.44269504088896340736f

__device__ __forceinline__ unsigned short cvt_bf16(float f) {
    __hip_bfloat16 h = __float2bfloat16(f);
    return *(unsigned short*)&h;
}
__device__ __forceinline__ unsigned int pk_bf16(float a, float b) {
    unsigned int lo = cvt_bf16(a), hi = cvt_bf16(b);
    return lo | (hi << 16);
}

// ---------------- phase 1: histogram of dst (both graphs) ----------------
__global__ __launch_bounds__(256) void hist_kernel(
    const int* __restrict__ ei_m, const int* __restrict__ ei_p,
    int* __restrict__ cnt_m, int* __restrict__ cnt_p)
{
    int idx = blockIdx.x * 256 + threadIdx.x;
    if (idx < EM) atomicAdd(&cnt_m[ei_m[EM + idx]], 1);
    int j = idx - EM;
    if (j >= 0 && j < EP) atomicAdd(&cnt_p[ei_p[EP + j]], 1);
}

// ---------------- phase 2: exclusive prefix sum (block 0 = mol, block 1 = prot) ----------------
__global__ __launch_bounds__(256) void scan_kernel(
    const int* __restrict__ cnt_m, const int* __restrict__ cnt_p,
    int* __restrict__ start_m, int* __restrict__ start_p,
    int* __restrict__ cur_m, int* __restrict__ cur_p)
{
    const int* cnt; int* start; int* cur; int n;
    if (blockIdx.x == 0) { cnt = cnt_m; start = start_m; cur = cur_m; n = NM; }
    else                 { cnt = cnt_p; start = start_p; cur = cur_p; n = NP; }
    int per = n >> 8;
    int tid = threadIdx.x;
    int base = tid * per;
    int s = 0;
    for (int i = 0; i < per; i++) s += cnt[base + i];
    __shared__ int wsum[4];
    int lane = tid & 63, w = tid >> 6;
    int v = s;
    #pragma unroll
    for (int off = 1; off < 64; off <<= 1) {
        int u = __shfl_up(v, off, 64);
        if (lane >= off) v += u;
    }
    if (lane == 63) wsum[w] = v;
    __syncthreads();
    int wo = 0;
    for (int i = 0; i < w; i++) wo += wsum[i];
    int run = wo + v - s;   // exclusive prefix for this thread's range
    for (int i = 0; i < per; i++) {
        start[base + i] = run; cur[base + i] = run;
        run += cnt[base + i];
    }
    if (tid == 255) start[n] = run;
}

// ---------------- phase 3: scatter edge ids (+src ids) into dst-sorted order ----------------
__global__ __launch_bounds__(256) void scatter_kernel(
    const int* __restrict__ ei_m, const int* __restrict__ ei_p,
    int* __restrict__ cur_m, int* __restrict__ cur_p,
    int* __restrict__ perm_m, int* __restrict__ perm_p,
    int* __restrict__ srcs_m, int* __restrict__ srcs_p)
{
    int idx = blockIdx.x * 256 + threadIdx.x;
    if (idx < EM) {
        int d = ei_m[EM + idx];
        int pos = atomicAdd(&cur_m[d], 1);
        perm_m[pos] = idx; srcs_m[pos] = ei_m[idx];
    }
    int j = idx - EM;
    if (j >= 0 && j < EP) {
        int d = ei_p[EP + j];
        int pos = atomicAdd(&cur_p[d], 1);
        perm_p[pos] = j; srcs_p[pos] = ei_p[j];
    }
}

// ---------------- phase 4: atomic-free segmented reduce; h0 = x + mean(relu(x[src]+ea)) -------
__global__ __launch_bounds__(256) void node_aggr_kernel(
    const float* __restrict__ x_m, const float* __restrict__ ea_m,
    const int* __restrict__ start_m, const int* __restrict__ perm_m, const int* __restrict__ srcs_m,
    const float* __restrict__ x_p, const float* __restrict__ ea_p,
    const int* __restrict__ start_p, const int* __restrict__ perm_p, const int* __restrict__ srcs_p,
    float* __restrict__ h0_m, float* __restrict__ h0_p)
{
    int wave = threadIdx.x >> 6, lane = threadIdx.x & 63;
    int nid = blockIdx.x * 4 + wave;
    const float *x, *ea; const int *start, *perm, *srcs; float* h0; int n;
    if (nid < NM) { x = x_m; ea = ea_m; start = start_m; perm = perm_m; srcs = srcs_m; h0 = h0_m; n = nid; }
    else          { x = x_p; ea = ea_p; start = start_p; perm = perm_p; srcs = srcs_p; h0 = h0_p; n = nid - NM; }
    int b = start[n], e = start[n + 1];
    int deg = e - b;
    float acc = 0.f;
    for (int c0 = 0; c0 < deg; c0 += 64) {
        int rem = deg - c0;
        int mcount = rem < 64 ? rem : 64;
        int eL = 0, sL = 0;
        if (lane < mcount) { eL = perm[b + c0 + lane]; sL = srcs[b + c0 + lane]; }
        int j = 0;
        for (; j + 3 < mcount; j += 4) {
            int e0 = __shfl(eL, j, 64),   e1 = __shfl(eL, j + 1, 64);
            int e2 = __shfl(eL, j + 2, 64), e3 = __shfl(eL, j + 3, 64);
            int s0 = __shfl(sL, j, 64),   s1 = __shfl(sL, j + 1, 64);
            int s2 = __shfl(sL, j + 2, 64), s3 = __shfl(sL, j + 3, 64);
            float a0 = ea[(size_t)e0 * 64 + lane], a1 = ea[(size_t)e1 * 64 + lane];
            float a2 = ea[(size_t)e2 * 64 + lane], a3 = ea[(size_t)e3 * 64 + lane];
            float y0 = x[(size_t)s0 * 64 + lane], y1 = x[(size_t)s1 * 64 + lane];
            float y2 = x[(size_t)s2 * 64 + lane], y3 = x[(size_t)s3 * 64 + lane];
            acc += fmaxf(y0 + a0, 0.f);
            acc += fmaxf(y1 + a1, 0.f);
            acc += fmaxf(y2 + a2, 0.f);
            acc += fmaxf(y3 + a3, 0.f);
        }
        for (; j < mcount; ++j) {
            int e0 = __shfl(eL, j, 64);
            int s0 = __shfl(sL, j, 64);
            acc += fmaxf(x[(size_t)s0 * 64 + lane] + ea[(size_t)e0 * 64 + lane], 0.f);
        }
    }
    float aggr = acc / fmaxf((float)deg, 1.f);
    h0[(size_t)n * 64 + lane] = x[(size_t)n * 64 + lane] + aggr;
}

// ---------------- GINE MLP (both graphs): h = relu( relu(h0@w1+b1)@w2 + b2 ) ----------------
__global__ __launch_bounds__(256) void gine_mlp_kernel(
    const float* __restrict__ h0_m, const float* __restrict__ h0_p,
    const float* __restrict__ w1m, const float* __restrict__ b1m,
    const float* __restrict__ w2m, const float* __restrict__ b2m,
    const float* __restrict__ w1p, const float* __restrict__ b1p,
    const float* __restrict__ w2p, const float* __restrict__ b2p,
    float* __restrict__ hm, float* __restrict__ hp)
{
    const float *h0, *w1, *b1, *w2, *b2; float* out; int row0;
    if (blockIdx.x < NM / 16) {
        h0 = h0_m; w1 = w1m; b1 = b1m; w2 = w2m; b2 = b2m; out = hm;
        row0 = blockIdx.x * 16;
    } else {
        h0 = h0_p; w1 = w1p; b1 = b1p; w2 = w2p; b2 = b2p; out = hp;
        row0 = (blockIdx.x - NM / 16) * 16;
    }
    __shared__ float sW1[4096], sW2[4096], sb1[64], sb2[64];
    __shared__ float sh0[16][64], sh1[16][64];
    int t = threadIdx.x;
    for (int i = t; i < 4096; i += 256) { sW1[i] = w1[i]; sW2[i] = w2[i]; }
    if (t < 64) { sb1[t] = b1[t]; sb2[t] = b2[t]; }
    for (int i = t; i < 16 * 64; i += 256) {
        int r = i >> 6, c = i & 63;
        sh0[r][c] = h0[(size_t)(row0 + r) * 64 + c];
    }
    __syncthreads();
    int j = t & 63, rs = t >> 6;
    for (int r = rs; r < 16; r += 4) {
        float a = sb1[j];
        #pragma unroll
        for (int c = 0; c < 64; c++) a += sh0[r][c] * sW1[c * 64 + j];
        sh1[r][j] = fmaxf(a, 0.0f);
    }
    __syncthreads();
    for (int r = rs; r < 16; r += 4) {
        float a = sb2[j];
        #pragma unroll
        for (int c = 0; c < 64; c++) a += sh1[r][c] * sW2[c * 64 + j];
        out[(size_t)(row0 + r) * 64 + j] = fmaxf(a, 0.0f);   // outer relu fused
    }
}

// -------- fused QKV -> bf16 (both sources). Q pre-scaled by 0.25*log2e (exp2 domain) --------
__global__ __launch_bounds__(256) void qkv_bf16_kernel(
    const float* __restrict__ hm, const float* __restrict__ hp,
    const float* __restrict__ wq_m, const float* __restrict__ bq_m,
    const float* __restrict__ wk_m, const float* __restrict__ bk_m,
    const float* __restrict__ wv_m, const float* __restrict__ bv_m,
    const float* __restrict__ wq_p, const float* __restrict__ bq_p,
    const float* __restrict__ wk_p, const float* __restrict__ bk_p,
    const float* __restrict__ wv_p, const float* __restrict__ bv_p,
    unsigned short* __restrict__ Qm, unsigned short* __restrict__ Km, unsigned short* __restrict__ Vtm,
    unsigned short* __restrict__ Qp, unsigned short* __restrict__ Kp, unsigned short* __restrict__ Vtp)
{
    const float *x, *wq, *bq, *wk, *bk, *wv, *bv;
    unsigned short *Q, *K, *Vt; int row0, N;
    if (blockIdx.x < NM / 16) {
        x = hm; wq = wq_m; bq = bq_m; wk = wk_m; bk = bk_m; wv = wv_m; bv = bv_m;
        Q = Qm; K = Km; Vt = Vtm; N = NM; row0 = blockIdx.x * 16;
    } else {
        x = hp; wq = wq_p; bq = bq_p; wk = wk_p; bk = bk_p; wv = wv_p; bv = bv_p;
        Q = Qp; K = Kp; Vt = Vtp; N = NP; row0 = (blockIdx.x - NM / 16) * 16;
    }
    __shared__ float sWq[4096], sWk[4096], sWv[4096];
    __shared__ float sbq[64], sbk[64], sbv[64];
    __shared__ float sh0[16][64];
    int t = threadIdx.x;
    for (int i = t; i < 4096; i += 256) { sWq[i] = wq[i]; sWk[i] = wk[i]; sWv[i] = wv[i]; }
    if (t < 64) { sbq[t] = bq[t]; sbk[t] = bk[t]; sbv[t] = bv[t]; }
    for (int i = t; i < 16 * 64; i += 256) {
        int r = i >> 6, c = i & 63;
        sh0[r][c] = x[(size_t)(row0 + r) * 64 + c];
    }
    __syncthreads();
    int j = t & 63, rs = t >> 6;
    for (int r = rs; r < 16; r += 4) {
        float aq = sbq[j], ak = sbk[j], av = sbv[j];
        #pragma unroll
        for (int c = 0; c < 64; c++) {
            float h = sh0[r][c];
            aq += h * sWq[c * 64 + j];
            ak += h * sWk[c * 64 + j];
            av += h * sWv[c * 64 + j];
        }
        size_t o = (size_t)(row0 + r) * 64 + j;
        Q[o] = cvt_bf16(aq * (0.25f * LOG2E));   // fold 1/sqrt(HD) and log2(e)
        K[o] = cvt_bf16(ak);
        Vt[(size_t)j * N + row0 + r] = cvt_bf16(av);
    }
}

// ---------------- MFMA flash-attention partial over a 1024-key chunk ----------------
// wave per task; S^T = K.Q^T keeps softmax per-lane; exp2 domain; K/Vt prefetch pipeline.
__global__ __launch_bounds__(256) void attn_partial_kernel(
    const unsigned short* __restrict__ Q, const unsigned short* __restrict__ K,
    const unsigned short* __restrict__ Vt, float* __restrict__ partial,
    int Nk, int ncbits)
{
    __shared__ unsigned int plds[4][16][20];   // per-wave P tile (bf16x2), 32 keys + pad
    int t = threadIdx.x;
    int wave = t >> 6;
    int lane = t & 63;
    int qrow = lane & 15;
    int quad = lane >> 4;
    int NC = 1 << ncbits;
    int task = blockIdx.x * 4 + wave;
    int chunk = task & (NC - 1);
    int tmp = task >> ncbits;
    int h = tmp & 3;
    int qt = tmp >> 2;

    short8 qf = {};
    if (quad < 2)
        qf = *(const short8*)(Q + ((size_t)(qt * 16 + qrow)) * 64 + h * 16 + quad * 8);

    float m = -3.0e38f, l = 0.0f;
    f32x4 acc = {0.f, 0.f, 0.f, 0.f};
    const f32x4 zero4 = {0.f, 0.f, 0.f, 0.f};
    int kbase = chunk * 1024;
    const unsigned short* vrow = Vt + ((size_t)(h * 16 + qrow)) * Nk;

    // prefetch iter 0
    short8 kf0n = {}, kf1n = {}, vfn;
    {
        int key0 = kbase;
        if (quad < 2) {
            kf0n = *(const short8*)(K + ((size_t)(key0 + qrow)) * 64 + h * 16 + quad * 8);
            kf1n = *(const short8*)(K + ((size_t)(key0 + 16 + qrow)) * 64 + h * 16 + quad * 8);
        }
        vfn = *(const short8*)(vrow + key0 + quad * 8);
    }

    for (int it = 0; it < 32; ++it) {
        short8 kf0 = kf0n, kf1 = kf1n, vf = vfn;
        if (it < 31) {
            int key0 = kbase + (it + 1) * 32;
            if (quad < 2) {
                kf0n = *(const short8*)(K + ((size_t)(key0 + qrow)) * 64 + h * 16 + quad * 8);
                kf1n = *(const short8*)(K + ((size_t)(key0 + 16 + qrow)) * 64 + h * 16 + quad * 8);
            }
            vfn = *(const short8*)(vrow + key0 + quad * 8);
        }

        f32x4 s0 = __builtin_amdgcn_mfma_f32_16x16x32_bf16(kf0, qf, zero4, 0, 0, 0);
        f32x4 s1 = __builtin_amdgcn_mfma_f32_16x16x32_bf16(kf1, qf, zero4, 0, 0, 0);

        float tmax = fmaxf(fmaxf(fmaxf(s0.x, s0.y), fmaxf(s0.z, s0.w)),
                           fmaxf(fmaxf(s1.x, s1.y), fmaxf(s1.z, s1.w)));
        tmax = fmaxf(tmax, __shfl_xor(tmax, 16, 64));
        tmax = fmaxf(tmax, __shfl_xor(tmax, 32, 64));
        float mnew = fmaxf(m, tmax);
        float alpha = exp2f(m - mnew);
        float p00 = exp2f(s0.x - mnew), p01 = exp2f(s0.y - mnew);
        float p02 = exp2f(s0.z - mnew), p03 = exp2f(s0.w - mnew);
        float p10 = exp2f(s1.x - mnew), p11 = exp2f(s1.y - mnew);
        float p12 = exp2f(s1.z - mnew), p13 = exp2f(s1.w - mnew);
        l = l * alpha + (((p00 + p01) + (p02 + p03)) + ((p10 + p11) + (p12 + p13)));
        acc.x *= alpha; acc.y *= alpha; acc.z *= alpha; acc.w *= alpha;

        plds[wave][qrow][quad * 2]     = pk_bf16(p00, p01);
        plds[wave][qrow][quad * 2 + 1] = pk_bf16(p02, p03);
        plds[wave][qrow][8 + quad * 2]     = pk_bf16(p10, p11);
        plds[wave][qrow][8 + quad * 2 + 1] = pk_bf16(p12, p13);
        short8 pf = *(short8*)&plds[wave][qrow][quad * 4];

        acc = __builtin_amdgcn_mfma_f32_16x16x32_bf16(vf, pf, acc, 0, 0, 0);
        m = mnew;
    }

    float ltot = l + __shfl_xor(l, 16, 64);
    ltot += __shfl_xor(ltot, 32, 64);

    float* pb = partial + (size_t)task * 288;
    *(f32x4*)&pb[qrow * 16 + quad * 4] = acc;
    if (quad == 0) { pb[256 + qrow] = m; pb[272 + qrow] = ltot; }
}

// ---------------- merge chunk partials + residual + layernorm ----------------
__global__ __launch_bounds__(256) void merge_ln_kernel(
    const float* __restrict__ partial, const float* __restrict__ hbuf,
    const float* __restrict__ g, const float* __restrict__ bia,
    float* __restrict__ out, int NC)
{
    int row = blockIdx.x * 4 + (threadIdx.x >> 6);
    int c = threadIdx.x & 63;
    int hi = c >> 4, d = c & 15;
    int qt = row >> 4, ql = row & 15;
    const float* base = partial + (size_t)(qt * 4 + hi) * NC * 288;
    float M = -3.0e38f;
    for (int cc = 0; cc < NC; ++cc) M = fmaxf(M, base[cc * 288 + 256 + ql]);
    float L = 0.0f, A = 0.0f;
    for (int cc = 0; cc < NC; ++cc) {
        float w = exp2f(base[cc * 288 + 256 + ql] - M);
        L += base[cc * 288 + 272 + ql] * w;
        A += base[cc * 288 + ql * 16 + d] * w;
    }
    float v = hbuf[(size_t)row * 64 + c] + A / L;
    float s = v;
    #pragma unroll
    for (int o = 32; o >= 1; o >>= 1) s += __shfl_xor(s, o, 64);
    float mu = s * (1.0f / 64.0f);
    float dv = v - mu;
    float sq = dv * dv;
    #pragma unroll
    for (int o = 32; o >= 1; o >>= 1) sq += __shfl_xor(sq, o, 64);
    float var = sq * (1.0f / 64.0f);
    out[(size_t)row * 64 + c] = dv * rsqrtf(var + 1e-5f) * g[c] + bia[c];
}

extern "C" void kernel_launch(void* const* d_in, const int* in_sizes, int n_in,
                              void* d_out, int out_size, void* d_ws, size_t ws_size,
                              hipStream_t stream)
{
    const float* x_mol   = (const float*)d_in[0];
    const int*   ei_mol  = (const int*)  d_in[1];
    const float* ea_mol  = (const float*)d_in[2];
    const float* x_prot  = (const float*)d_in[3];
    const int*   ei_prot = (const int*)  d_in[4];
    const float* ea_prot = (const float*)d_in[5];
    const float* mol_w1  = (const float*)d_in[6];
    const float* mol_b1  = (const float*)d_in[7];
    const float* mol_w2  = (const float*)d_in[8];
    const float* mol_b2  = (const float*)d_in[9];
    const float* prot_w1 = (const float*)d_in[10];
    const float* prot_b1 = (const float*)d_in[11];
    const float* prot_w2 = (const float*)d_in[12];
    const float* prot_b2 = (const float*)d_in[13];
    const float* mp_wq = (const float*)d_in[14]; const float* mp_bq = (const float*)d_in[15];
    const float* mp_wk = (const float*)d_in[16]; const float* mp_bk = (const float*)d_in[17];
    const float* mp_wv = (const float*)d_in[18]; const float* mp_bv = (const float*)d_in[19];
    const float* pm_wq = (const float*)d_in[20]; const float* pm_bq = (const float*)d_in[21];
    const float* pm_wk = (const float*)d_in[22]; const float* pm_bk = (const float*)d_in[23];
    const float* pm_wv = (const float*)d_in[24]; const float* pm_bv = (const float*)d_in[25];
    const float* ln_mol_g  = (const float*)d_in[26];
    const float* ln_mol_b  = (const float*)d_in[27];
    const float* ln_prot_g = (const float*)d_in[28];
    const float* ln_prot_b = (const float*)d_in[29];

    float* ws = (float*)d_ws;
    // float region
    float* h_mol   = ws;                         // 131072
    float* h_prot  = h_mol + 131072;             // 524288
    float* partial = h_prot + 524288;            // 1179648 (attn partials; earlier: h0 buffers)
    float* h0_mol  = partial;                    // 131072  (dead before attn writes partial)
    float* h0_prot = h0_mol + 131072;            // 524288
    // int region (byte offset 7,340,032)
    int* ip      = (int*)(partial + 1179648);
    int* cnt_m   = ip;                 // 2048
    int* cnt_p   = cnt_m + 2048;       // 8192
    int* start_m = cnt_p + 8192;       // 2052 (2049 used)
    int* start_p = start_m + 2052;     // 8196 (8193 used)
    int* cur_m   = start_p + 8196;     // 2048
    int* cur_p   = cur_m + 2048;       // 8192
    int* perm_m  = cur_p + 8192;       // 32768
    int* perm_p  = perm_m + 32768;     // 262144
    int* srcs_m  = perm_p + 262144;    // 32768
    int* srcs_p  = srcs_m + 32768;     // 262144
    // bf16 region (16B-aligned)
    unsigned short* bf = (unsigned short*)(srcs_p + 262144);
    unsigned short* Qm  = bf;            // 131072
    unsigned short* Km  = Qm + 131072;   // 131072
    unsigned short* Vtm = Km + 131072;   // 131072  [64][NM]
    unsigned short* Qp  = Vtm + 131072;  // 524288
    unsigned short* Kp  = Qp + 524288;   // 524288
    unsigned short* Vtp = Kp + 524288;   // 524288  [64][NP]

    // zero only the histogram counters
    hipMemsetAsync(cnt_m, 0, (size_t)(2048 + 8192) * sizeof(int), stream);

    const int EB = (EM + EP) / 256;   // 1152
    hist_kernel<<<EB, 256, 0, stream>>>(ei_mol, ei_prot, cnt_m, cnt_p);
    scan_kernel<<<2, 256, 0, stream>>>(cnt_m, cnt_p, start_m, start_p, cur_m, cur_p);
    scatter_kernel<<<EB, 256, 0, stream>>>(ei_mol, ei_prot, cur_m, cur_p, perm_m, perm_p, srcs_m, srcs_p);
    node_aggr_kernel<<<(NM + NP) / 4, 256, 0, stream>>>(
        x_mol, ea_mol, start_m, perm_m, srcs_m,
        x_prot, ea_prot, start_p, perm_p, srcs_p, h0_mol, h0_prot);

    gine_mlp_kernel<<<(NM + NP) / 16, 256, 0, stream>>>(
        h0_mol, h0_prot, mol_w1, mol_b1, mol_w2, mol_b2,
        prot_w1, prot_b1, prot_w2, prot_b2, h_mol, h_prot);

    // mol-source: Q for mol->prot, K/V for prot->mol; prot-source: Q for prot->mol, K/V for mol->prot
    qkv_bf16_kernel<<<(NM + NP) / 16, 256, 0, stream>>>(
        h_mol, h_prot,
        mp_wq, mp_bq, pm_wk, pm_bk, pm_wv, pm_bv,
        pm_wq, pm_bq, mp_wk, mp_bk, mp_wv, mp_bv,
        Qm, Km, Vtm, Qp, Kp, Vtp);

    float* out = (float*)d_out;

    // mol->prot: 128 qt x 4 h x NC=8 chunks of 1024 -> 4096 tasks
    attn_partial_kernel<<<1024, 256, 0, stream>>>(Qm, Kp, Vtp, partial, NP, 3);
    merge_ln_kernel<<<NM / 4, 256, 0, stream>>>(partial, h_mol, ln_mol_g, ln_mol_b, out, 8);

    // prot->mol: 512 qt x 4 h x NC=2 chunks of 1024 -> 4096 tasks
    attn_partial_kernel<<<1024, 256, 0, stream>>>(Qp, Km, Vtm, partial, NM, 1);
    merge_ln_kernel<<<NP / 4, 256, 0, stream>>>(partial, h_prot, ln_prot_g, ln_prot_b, out + 131072, 2);
}

// Round 4
// 323.304 us; speedup vs baseline: 2.7198x; 1.0306x over previous
//
#include <hip/hip_runtime.h>

#define NM 2048
#define EM 32768
#define NP 8192
#define EP 262144

typedef __attribute__((ext_vector_type(8))) short short8;
typedef __attribute__((ext_vector_type(4))) float f32x4;

#define LOG2E 1.44269504088896340736f

__device__ __forceinline__ float e2(float x) { return __builtin_amdgcn_exp2f(x); }
// pack two fp32 -> bf16x2 (round-half-up): 3 insts
__device__ __forceinline__ unsigned int pk_bf16(float a, float b) {
    unsigned int ua = __float_as_uint(a) + 0x8000u;
    unsigned int ub = __float_as_uint(b) + 0x8000u;
    return __builtin_amdgcn_perm(ua, ub, 0x03020706u);  // low16=a.hi, high16=b.hi
}
__device__ __forceinline__ unsigned short cvt_bf16(float f) {
    unsigned int u = __float_as_uint(f);
    u = (u + 0x7fff + ((u >> 16) & 1)) >> 16;   // RNE
    return (unsigned short)u;
}

// ---------------- phase 1: histogram of dst (both graphs) ----------------
__global__ __launch_bounds__(256) void hist_kernel(
    const int* __restrict__ ei_m, const int* __restrict__ ei_p,
    int* __restrict__ cnt_m, int* __restrict__ cnt_p)
{
    int idx = blockIdx.x * 256 + threadIdx.x;
    if (idx < EM) atomicAdd(&cnt_m[ei_m[EM + idx]], 1);
    int j = idx - EM;
    if (j >= 0 && j < EP) atomicAdd(&cnt_p[ei_p[EP + j]], 1);
}

// ---------------- phase 2: exclusive prefix sum (block 0 = mol, block 1 = prot) ----------------
__global__ __launch_bounds__(256) void scan_kernel(
    const int* __restrict__ cnt_m, const int* __restrict__ cnt_p,
    int* __restrict__ start_m, int* __restrict__ start_p,
    int* __restrict__ cur_m, int* __restrict__ cur_p)
{
    const int* cnt; int* start; int* cur; int n;
    if (blockIdx.x == 0) { cnt = cnt_m; start = start_m; cur = cur_m; n = NM; }
    else                 { cnt = cnt_p; start = start_p; cur = cur_p; n = NP; }
    int per = n >> 8;
    int tid = threadIdx.x;
    int base = tid * per;
    int s = 0;
    for (int i = 0; i < per; i++) s += cnt[base + i];
    __shared__ int wsum[4];
    int lane = tid & 63, w = tid >> 6;
    int v = s;
    #pragma unroll
    for (int off = 1; off < 64; off <<= 1) {
        int u = __shfl_up(v, off, 64);
        if (lane >= off) v += u;
    }
    if (lane == 63) wsum[w] = v;
    __syncthreads();
    int wo = 0;
    for (int i = 0; i < w; i++) wo += wsum[i];
    int run = wo + v - s;   // exclusive prefix for this thread's range
    for (int i = 0; i < per; i++) {
        start[base + i] = run; cur[base + i] = run;
        run += cnt[base + i];
    }
    if (tid == 255) start[n] = run;
}

// ------- phase 3: scatter packed (edge<<sh)|src into dst-sorted order -------
__global__ __launch_bounds__(256) void scatter_kernel(
    const int* __restrict__ ei_m, const int* __restrict__ ei_p,
    int* __restrict__ cur_m, int* __restrict__ cur_p,
    int* __restrict__ pidx_m, int* __restrict__ pidx_p)
{
    int idx = blockIdx.x * 256 + threadIdx.x;
    if (idx < EM) {
        int d = ei_m[EM + idx];
        int pos = atomicAdd(&cur_m[d], 1);
        pidx_m[pos] = (idx << 11) | ei_m[idx];          // NM=2048 -> 11 src bits
    }
    int j = idx - EM;
    if (j >= 0 && j < EP) {
        int d = ei_p[EP + j];
        int pos = atomicAdd(&cur_p[d], 1);
        pidx_p[pos] = (j << 13) | ei_p[j];              // NP=8192 -> 13 src bits
    }
}

// ------- phase 4: atomic-free segmented reduce; h0 = x + mean(relu(x[src]+ea)) -------
__global__ __launch_bounds__(256) void node_aggr_kernel(
    const float* __restrict__ x_m, const float* __restrict__ ea_m,
    const int* __restrict__ start_m, const int* __restrict__ pidx_m,
    const float* __restrict__ x_p, const float* __restrict__ ea_p,
    const int* __restrict__ start_p, const int* __restrict__ pidx_p,
    float* __restrict__ h0_m, float* __restrict__ h0_p)
{
    int wave = threadIdx.x >> 6, lane = threadIdx.x & 63;
    int nid = blockIdx.x * 4 + wave;
    const float *x, *ea; const int *start, *pidx; float* h0; int n, sh, msk;
    if (nid < NM) { x = x_m; ea = ea_m; start = start_m; pidx = pidx_m; h0 = h0_m; n = nid; sh = 11; msk = 2047; }
    else          { x = x_p; ea = ea_p; start = start_p; pidx = pidx_p; h0 = h0_p; n = nid - NM; sh = 13; msk = 8191; }
    int b = start[n], e = start[n + 1];
    int deg = e - b;
    float acc = 0.f;
    for (int c0 = 0; c0 < deg; c0 += 64) {
        int rem = deg - c0;
        int mcount = rem < 64 ? rem : 64;
        int pk = 0;
        if (lane < mcount) pk = pidx[b + c0 + lane];
        int j = 0;
        for (; j + 3 < mcount; j += 4) {
            int v0 = __shfl(pk, j, 64),     v1 = __shfl(pk, j + 1, 64);
            int v2 = __shfl(pk, j + 2, 64), v3 = __shfl(pk, j + 3, 64);
            float a0 = ea[(size_t)(((unsigned)v0) >> sh) * 64 + lane];
            float a1 = ea[(size_t)(((unsigned)v1) >> sh) * 64 + lane];
            float a2 = ea[(size_t)(((unsigned)v2) >> sh) * 64 + lane];
            float a3 = ea[(size_t)(((unsigned)v3) >> sh) * 64 + lane];
            float y0 = x[(size_t)(v0 & msk) * 64 + lane];
            float y1 = x[(size_t)(v1 & msk) * 64 + lane];
            float y2 = x[(size_t)(v2 & msk) * 64 + lane];
            float y3 = x[(size_t)(v3 & msk) * 64 + lane];
            acc += fmaxf(y0 + a0, 0.f);
            acc += fmaxf(y1 + a1, 0.f);
            acc += fmaxf(y2 + a2, 0.f);
            acc += fmaxf(y3 + a3, 0.f);
        }
        for (; j < mcount; ++j) {
            int v0 = __shfl(pk, j, 64);
            acc += fmaxf(x[(size_t)(v0 & msk) * 64 + lane] + ea[(size_t)(((unsigned)v0) >> sh) * 64 + lane], 0.f);
        }
    }
    float aggr = acc / fmaxf((float)deg, 1.f);
    h0[(size_t)n * 64 + lane] = x[(size_t)n * 64 + lane] + aggr;
}

// ---------------- GINE MLP (both graphs): h = relu( relu(h0@w1+b1)@w2 + b2 ) ----------------
__global__ __launch_bounds__(256) void gine_mlp_kernel(
    const float* __restrict__ h0_m, const float* __restrict__ h0_p,
    const float* __restrict__ w1m, const float* __restrict__ b1m,
    const float* __restrict__ w2m, const float* __restrict__ b2m,
    const float* __restrict__ w1p, const float* __restrict__ b1p,
    const float* __restrict__ w2p, const float* __restrict__ b2p,
    float* __restrict__ hm, float* __restrict__ hp)
{
    const float *h0, *w1, *b1, *w2, *b2; float* out; int row0;
    if (blockIdx.x < NM / 16) {
        h0 = h0_m; w1 = w1m; b1 = b1m; w2 = w2m; b2 = b2m; out = hm;
        row0 = blockIdx.x * 16;
    } else {
        h0 = h0_p; w1 = w1p; b1 = b1p; w2 = w2p; b2 = b2p; out = hp;
        row0 = (blockIdx.x - NM / 16) * 16;
    }
    __shared__ float sW1[4096], sW2[4096], sb1[64], sb2[64];
    __shared__ float sh0[16][64], sh1[16][64];
    int t = threadIdx.x;
    for (int i = t; i < 4096; i += 256) { sW1[i] = w1[i]; sW2[i] = w2[i]; }
    if (t < 64) { sb1[t] = b1[t]; sb2[t] = b2[t]; }
    for (int i = t; i < 16 * 64; i += 256) {
        int r = i >> 6, c = i & 63;
        sh0[r][c] = h0[(size_t)(row0 + r) * 64 + c];
    }
    __syncthreads();
    int j = t & 63, rs = t >> 6;
    for (int r = rs; r < 16; r += 4) {
        float a = sb1[j];
        #pragma unroll
        for (int c = 0; c < 64; c++) a += sh0[r][c] * sW1[c * 64 + j];
        sh1[r][j] = fmaxf(a, 0.0f);
    }
    __syncthreads();
    for (int r = rs; r < 16; r += 4) {
        float a = sb2[j];
        #pragma unroll
        for (int c = 0; c < 64; c++) a += sh1[r][c] * sW2[c * 64 + j];
        out[(size_t)(row0 + r) * 64 + j] = fmaxf(a, 0.0f);   // outer relu fused
    }
}

// -------- fused QKV -> bf16 (both sources). Q pre-scaled by 0.25*log2e (exp2 domain) --------
__global__ __launch_bounds__(256) void qkv_bf16_kernel(
    const float* __restrict__ hm, const float* __restrict__ hp,
    const float* __restrict__ wq_m, const float* __restrict__ bq_m,
    const float* __restrict__ wk_m, const float* __restrict__ bk_m,
    const float* __restrict__ wv_m, const float* __restrict__ bv_m,
    const float* __restrict__ wq_p, const float* __restrict__ bq_p,
    const float* __restrict__ wk_p, const float* __restrict__ bk_p,
    const float* __restrict__ wv_p, const float* __restrict__ bv_p,
    unsigned short* __restrict__ Qm, unsigned short* __restrict__ Km, unsigned short* __restrict__ Vtm,
    unsigned short* __restrict__ Qp, unsigned short* __restrict__ Kp, unsigned short* __restrict__ Vtp)
{
    const float *x, *wq, *bq, *wk, *bk, *wv, *bv;
    unsigned short *Q, *K, *Vt; int row0, N;
    if (blockIdx.x < NM / 16) {
        x = hm; wq = wq_m; bq = bq_m; wk = wk_m; bk = bk_m; wv = wv_m; bv = bv_m;
        Q = Qm; K = Km; Vt = Vtm; N = NM; row0 = blockIdx.x * 16;
    } else {
        x = hp; wq = wq_p; bq = bq_p; wk = wk_p; bk = bk_p; wv = wv_p; bv = bv_p;
        Q = Qp; K = Kp; Vt = Vtp; N = NP; row0 = (blockIdx.x - NM / 16) * 16;
    }
    __shared__ float sWq[4096], sWk[4096], sWv[4096];
    __shared__ float sbq[64], sbk[64], sbv[64];
    __shared__ float sh0[16][64];
    int t = threadIdx.x;
    for (int i = t; i < 4096; i += 256) { sWq[i] = wq[i]; sWk[i] = wk[i]; sWv[i] = wv[i]; }
    if (t < 64) { sbq[t] = bq[t]; sbk[t] = bk[t]; sbv[t] = bv[t]; }
    for (int i = t; i < 16 * 64; i += 256) {
        int r = i >> 6, c = i & 63;
        sh0[r][c] = x[(size_t)(row0 + r) * 64 + c];
    }
    __syncthreads();
    int j = t & 63, rs = t >> 6;
    for (int r = rs; r < 16; r += 4) {
        float aq = sbq[j], ak = sbk[j], av = sbv[j];
        #pragma unroll
        for (int c = 0; c < 64; c++) {
            float h = sh0[r][c];
            aq += h * sWq[c * 64 + j];
            ak += h * sWk[c * 64 + j];
            av += h * sWv[c * 64 + j];
        }
        size_t o = (size_t)(row0 + r) * 64 + j;
        Q[o] = cvt_bf16(aq * (0.25f * LOG2E));   // fold 1/sqrt(HD) and log2(e)
        K[o] = cvt_bf16(ak);
        Vt[(size_t)j * N + row0 + r] = cvt_bf16(av);
    }
}

// ---------------- fused MFMA flash-attention (both directions, one dispatch) ----------------
// 8192 wave-tasks: T<4096 mol->prot (NC=8), else prot->mol (NC=2); 1024 keys/task.
__global__ __launch_bounds__(256) void attn_kernel(
    const unsigned short* __restrict__ Qm, const unsigned short* __restrict__ Km,
    const unsigned short* __restrict__ Vtm,
    const unsigned short* __restrict__ Qp, const unsigned short* __restrict__ Kp,
    const unsigned short* __restrict__ Vtp,
    float* __restrict__ partial)
{
    __shared__ unsigned int plds[4][16][20];
    int t = threadIdx.x;
    int wave = t >> 6;
    int lane = t & 63;
    int qrow = lane & 15;
    int quad = lane >> 4;
    int T = blockIdx.x * 4 + wave;

    const unsigned short *Q, *K, *Vt; int Nk, ncb, tloc;
    if (T < 4096) { Q = Qm; K = Kp; Vt = Vtp; Nk = NP; ncb = 3; tloc = T; }
    else          { Q = Qp; K = Km; Vt = Vtm; Nk = NM; ncb = 1; tloc = T - 4096; }
    int chunk = tloc & ((1 << ncb) - 1);
    int tmp = tloc >> ncb;
    int h = tmp & 3;
    int qt = tmp >> 2;

    short8 qf = {};
    if (quad < 2)
        qf = *(const short8*)(Q + ((size_t)(qt * 16 + qrow)) * 64 + h * 16 + quad * 8);

    float m = -3.0e38f, l = 0.0f;
    f32x4 acc = {0.f, 0.f, 0.f, 0.f};
    const f32x4 zero4 = {0.f, 0.f, 0.f, 0.f};
    int kbase = chunk * 1024;
    const unsigned short* vrow = Vt + ((size_t)(h * 16 + qrow)) * Nk;

    short8 kf0n = {}, kf1n = {}, vfn;
    {
        if (quad < 2) {
            kf0n = *(const short8*)(K + ((size_t)(kbase + qrow)) * 64 + h * 16 + quad * 8);
            kf1n = *(const short8*)(K + ((size_t)(kbase + 16 + qrow)) * 64 + h * 16 + quad * 8);
        }
        vfn = *(const short8*)(vrow + kbase + quad * 8);
    }

    for (int it = 0; it < 32; ++it) {
        short8 kf0 = kf0n, kf1 = kf1n, vf = vfn;
        if (it < 31) {
            int key0 = kbase + (it + 1) * 32;
            if (quad < 2) {
                kf0n = *(const short8*)(K + ((size_t)(key0 + qrow)) * 64 + h * 16 + quad * 8);
                kf1n = *(const short8*)(K + ((size_t)(key0 + 16 + qrow)) * 64 + h * 16 + quad * 8);
            }
            vfn = *(const short8*)(vrow + key0 + quad * 8);
        }

        f32x4 s0 = __builtin_amdgcn_mfma_f32_16x16x32_bf16(kf0, qf, zero4, 0, 0, 0);
        f32x4 s1 = __builtin_amdgcn_mfma_f32_16x16x32_bf16(kf1, qf, zero4, 0, 0, 0);

        // 8-value max: 2 levels of max3 + pairwise
        float tmax = fmaxf(fmaxf(fmaxf(s0.x, s0.y), fmaxf(s0.z, s0.w)),
                           fmaxf(fmaxf(s1.x, s1.y), fmaxf(s1.z, s1.w)));
        tmax = fmaxf(tmax, __shfl_xor(tmax, 16, 64));
        tmax = fmaxf(tmax, __shfl_xor(tmax, 32, 64));
        float mnew = fmaxf(m, tmax);
        float alpha = e2(m - mnew);
        float p00 = e2(s0.x - mnew), p01 = e2(s0.y - mnew);
        float p02 = e2(s0.z - mnew), p03 = e2(s0.w - mnew);
        float p10 = e2(s1.x - mnew), p11 = e2(s1.y - mnew);
        float p12 = e2(s1.z - mnew), p13 = e2(s1.w - mnew);
        l = l * alpha + (((p00 + p01) + (p02 + p03)) + ((p10 + p11) + (p12 + p13)));
        acc.x *= alpha; acc.y *= alpha; acc.z *= alpha; acc.w *= alpha;

        // pack P -> LDS (bf16x2 words; word W holds keys 2W,2W+1)
        uint2 w0; w0.x = pk_bf16(p00, p01); w0.y = pk_bf16(p02, p03);
        uint2 w1; w1.x = pk_bf16(p10, p11); w1.y = pk_bf16(p12, p13);
        *(uint2*)&plds[wave][qrow][quad * 2] = w0;
        *(uint2*)&plds[wave][qrow][8 + quad * 2] = w1;
        short8 pf = *(short8*)&plds[wave][qrow][quad * 4];   // B[k=quad*8+j][n=qrow]

        acc = __builtin_amdgcn_mfma_f32_16x16x32_bf16(vf, pf, acc, 0, 0, 0);
        m = mnew;
    }

    float ltot = l + __shfl_xor(l, 16, 64);
    ltot += __shfl_xor(ltot, 32, 64);

    float* pb = partial + (size_t)T * 288;
    *(f32x4*)&pb[qrow * 16 + quad * 4] = acc;
    if (quad == 0) { pb[256 + qrow] = m; pb[272 + qrow] = ltot; }
}

// ---------------- merge chunk partials + residual + layernorm (both dirs) ----------------
__global__ __launch_bounds__(256) void merge_ln_kernel(
    const float* __restrict__ partial,
    const float* __restrict__ h_m, const float* __restrict__ h_p,
    const float* __restrict__ gm, const float* __restrict__ bm,
    const float* __restrict__ gp, const float* __restrict__ bp_,
    float* __restrict__ out)
{
    int t = threadIdx.x;
    int grow = blockIdx.x * 4 + (t >> 6);
    int c = t & 63;
    const float *pbase, *hbuf, *g, *bb; float* o; int NC, row;
    if (grow < NM) { pbase = partial;               hbuf = h_m; g = gm; bb = bm;  o = out;             NC = 8; row = grow; }
    else           { pbase = partial + 4096 * 288;  hbuf = h_p; g = gp; bb = bp_; o = out + NM * 64;   NC = 2; row = grow - NM; }
    int hi = c >> 4, d = c & 15;
    int qt = row >> 4, ql = row & 15;
    const float* base = pbase + (size_t)(qt * 4 + hi) * NC * 288;
    float M = -3.0e38f;
    for (int cc = 0; cc < NC; ++cc) M = fmaxf(M, base[cc * 288 + 256 + ql]);
    float L = 0.0f, A = 0.0f;
    for (int cc = 0; cc < NC; ++cc) {
        float w = e2(base[cc * 288 + 256 + ql] - M);
        L += base[cc * 288 + 272 + ql] * w;
        A += base[cc * 288 + ql * 16 + d] * w;
    }
    float v = hbuf[(size_t)row * 64 + c] + A / L;
    float s = v;
    #pragma unroll
    for (int o2 = 32; o2 >= 1; o2 >>= 1) s += __shfl_xor(s, o2, 64);
    float mu = s * (1.0f / 64.0f);
    float dv = v - mu;
    float sq = dv * dv;
    #pragma unroll
    for (int o2 = 32; o2 >= 1; o2 >>= 1) sq += __shfl_xor(sq, o2, 64);
    float var = sq * (1.0f / 64.0f);
    o[(size_t)row * 64 + c] = dv * rsqrtf(var + 1e-5f) * g[c] + bb[c];
}

extern "C" void kernel_launch(void* const* d_in, const int* in_sizes, int n_in,
                              void* d_out, int out_size, void* d_ws, size_t ws_size,
                              hipStream_t stream)
{
    const float* x_mol   = (const float*)d_in[0];
    const int*   ei_mol  = (const int*)  d_in[1];
    const float* ea_mol  = (const float*)d_in[2];
    const float* x_prot  = (const float*)d_in[3];
    const int*   ei_prot = (const int*)  d_in[4];
    const float* ea_prot = (const float*)d_in[5];
    const float* mol_w1  = (const float*)d_in[6];
    const float* mol_b1  = (const float*)d_in[7];
    const float* mol_w2  = (const float*)d_in[8];
    const float* mol_b2  = (const float*)d_in[9];
    const float* prot_w1 = (const float*)d_in[10];
    const float* prot_b1 = (const float*)d_in[11];
    const float* prot_w2 = (const float*)d_in[12];
    const float* prot_b2 = (const float*)d_in[13];
    const float* mp_wq = (const float*)d_in[14]; const float* mp_bq = (const float*)d_in[15];
    const float* mp_wk = (const float*)d_in[16]; const float* mp_bk = (const float*)d_in[17];
    const float* mp_wv = (const float*)d_in[18]; const float* mp_bv = (const float*)d_in[19];
    const float* pm_wq = (const float*)d_in[20]; const float* pm_bq = (const float*)d_in[21];
    const float* pm_wk = (const float*)d_in[22]; const float* pm_bk = (const float*)d_in[23];
    const float* pm_wv = (const float*)d_in[24]; const float* pm_bv = (const float*)d_in[25];
    const float* ln_mol_g  = (const float*)d_in[26];
    const float* ln_mol_b  = (const float*)d_in[27];
    const float* ln_prot_g = (const float*)d_in[28];
    const float* ln_prot_b = (const float*)d_in[29];

    float* ws = (float*)d_ws;
    // float region
    float* h_mol   = ws;                         // 131072
    float* h_prot  = h_mol + 131072;             // 524288
    float* partial = h_prot + 524288;            // 8192*288 = 2359296 (mol rows 0..4095, prot 4096..8191)
    float* h0_mol  = partial;                    // alias: dead before attn writes
    float* h0_prot = h0_mol + 131072;
    // int region
    int* ip      = (int*)(partial + 2359296);
    int* cnt_m   = ip;                 // 2048
    int* cnt_p   = cnt_m + 2048;       // 8192
    int* start_m = cnt_p + 8192;       // 2052 (2049 used)
    int* start_p = start_m + 2052;     // 8196 (8193 used)
    int* cur_m   = start_p + 8196;     // 2048
    int* cur_p   = cur_m + 2048;       // 8192
    int* pidx_m  = cur_p + 8192;       // 32768  packed (edge<<11)|src
    int* pidx_p  = pidx_m + 32768;     // 262144 packed (edge<<13)|src
    // bf16 region (16B-aligned by construction)
    unsigned short* bf = (unsigned short*)(pidx_p + 262144);
    unsigned short* Qm  = bf;            // 131072
    unsigned short* Km  = Qm + 131072;   // 131072
    unsigned short* Vtm = Km + 131072;   // 131072  [64][NM]
    unsigned short* Qp  = Vtm + 131072;  // 524288
    unsigned short* Kp  = Qp + 524288;   // 524288
    unsigned short* Vtp = Kp + 524288;   // 524288  [64][NP]

    hipMemsetAsync(cnt_m, 0, (size_t)(2048 + 8192) * sizeof(int), stream);

    const int EB = (EM + EP) / 256;   // 1152
    hist_kernel<<<EB, 256, 0, stream>>>(ei_mol, ei_prot, cnt_m, cnt_p);
    scan_kernel<<<2, 256, 0, stream>>>(cnt_m, cnt_p, start_m, start_p, cur_m, cur_p);
    scatter_kernel<<<EB, 256, 0, stream>>>(ei_mol, ei_prot, cur_m, cur_p, pidx_m, pidx_p);
    node_aggr_kernel<<<(NM + NP) / 4, 256, 0, stream>>>(
        x_mol, ea_mol, start_m, pidx_m,
        x_prot, ea_prot, start_p, pidx_p, h0_mol, h0_prot);

    gine_mlp_kernel<<<(NM + NP) / 16, 256, 0, stream>>>(
        h0_mol, h0_prot, mol_w1, mol_b1, mol_w2, mol_b2,
        prot_w1, prot_b1, prot_w2, prot_b2, h_mol, h_prot);

    qkv_bf16_kernel<<<(NM + NP) / 16, 256, 0, stream>>>(
        h_mol, h_prot,
        mp_wq, mp_bq, pm_wk, pm_bk, pm_wv, pm_bv,
        pm_wq, pm_bq, mp_wk, mp_bk, mp_wv, mp_bv,
        Qm, Km, Vtm, Qp, Kp, Vtp);

    // both attention directions in one dispatch: 2048 blocks x 4 waves = 8192 tasks
    attn_kernel<<<2048, 256, 0, stream>>>(Qm, Km, Vtm, Qp, Kp, Vtp, partial);

    float* out = (float*)d_out;
    merge_ln_kernel<<<(NM + NP) / 4, 256, 0, stream>>>(
        partial, h_mol, h_prot, ln_mol_g, ln_mol_b, ln_prot_g, ln_prot_b, out);
}